// Round 5
// baseline (107.663 us; speedup 1.0000x reference)
//
#include <hip/hip_runtime.h>
#include <math.h>

// Problem constants (fixed by the reference): Q=4096 queries, N=65536 train, D=32.
#define QN 4096
#define NN 65536
#define DD 32

typedef __attribute__((ext_vector_type(8))) _Float16 half8;
typedef __attribute__((ext_vector_type(4))) _Float16 half4v;
typedef __attribute__((ext_vector_type(4))) float floatx4;
typedef __attribute__((ext_vector_type(2))) float floatx2;

#define LOG2E 1.4426950408889634f
#define HALF_D_LOG_2PI 29.40603306254953f   // 16 * ln(2*pi)

// exp2-in-MFMA scaling: A = x*log2(e)*2^11, B = y*2^12, C = 127*2^23.
// MFMA emits v = (127 + x.y*log2e)*2^23 == the float bit pattern of
// 2^(x.y*log2e) under the linear-mantissa approximation.
// Epilogue per element: one v_cvt_u32_f32 (saturating: neg -> 0, standing
// in for the load-bearing lower clamp) + HALF a v_pk_fma_f32 (R15: packed
// f32 FMA pairs rows r={0,1} and r={2,3}; c_j stored pre-duplicated as
// float2 so the splat pair comes straight from a dwordx2 load).
#define ASCALE 2954.6394357789634f   // log2(e) * 2048
#define BSCALE 4096.0f               // 2^12
#define BIAS_F 1065353216.0f         // 127 * 2^23
#define CENTER 0.970656f             // centers the one-sided approx error

__device__ __forceinline__ float fexp_term(float v) {
    unsigned u;
    asm("v_cvt_u32_f32 %0, %1" : "=v"(u) : "v"(v));  // saturating: neg -> 0
    return __uint_as_float(u);
}

// s += c * e, two f32 lanes per instruction (VOP3P packed FP32).
__device__ __forceinline__ void pk_fma(floatx2& s, floatx2 c, floatx2 e) {
    asm("v_pk_fma_f32 %0, %1, %2, %0" : "+v"(s) : "v"(c), "v"(e));
}

// ---------------------------------------------------------------------------
// Workspace layout (bytes):
//   Xh    @ 0        : QN*DD*2 = 262144   (_Float16, X * ASCALE)
//   Xth   @ 262144   : NN*DD*2 = 4194304  (_Float16, X_train * BSCALE)
//   c2    @ 4456448  : NN*8    = 524288   (float2 {c_j, c_j},
//                                          c_j = CENTER*w_j*exp(-||y_j||^2/2))
//   qn    @ 4980736  : QN*4    = 16384    (||x_i||^2 / 2, nat units)
//   S     @ 4997120  : QN*4    = 16384    (zeroed by prep_all)
//   swp   @ 5013504  : 64*4    = 256      (per-block partial sums of w)
// kde_main's prefetch over-reads <= 1 pair past the strip end; for the last
// strip the b-over-read lands in c2 and the c-over-read lands in qn --
// both in-bounds, values discarded.
// ---------------------------------------------------------------------------

__global__ __launch_bounds__(256) void prep_all(
    const float* __restrict__ X, const float* __restrict__ Xt,
    const float* __restrict__ w, _Float16* __restrict__ Xh,
    float* __restrict__ qn, _Float16* __restrict__ Xth,
    float* __restrict__ c2, float* __restrict__ S,
    float* __restrict__ swp) {
    const int b = blockIdx.x;
    if (b < 128) {                       // ---- prep X: QN rows, 8 lanes/row
        int tid  = b * 256 + threadIdx.x;
        int row  = tid >> 3;
        int part = tid & 7;
        const float4 v = ((const float4*)X)[row * 8 + part];
        float nrm = v.x * v.x + v.y * v.y + v.z * v.z + v.w * v.w;
        nrm += __shfl_xor(nrm, 1);
        nrm += __shfl_xor(nrm, 2);
        nrm += __shfl_xor(nrm, 4);
        half4v h = { (_Float16)(v.x * ASCALE), (_Float16)(v.y * ASCALE),
                     (_Float16)(v.z * ASCALE), (_Float16)(v.w * ASCALE) };
        *(half4v*)(Xh + row * DD + part * 4) = h;
        if (part == 0) qn[row] = 0.5f * nrm;
        if (tid < QN) S[tid] = 0.f;      // fused zeroing of S
    } else if (b < 2176) {               // ---- prep X_train: NN rows
        int tid  = (b - 128) * 256 + threadIdx.x;
        int row  = tid >> 3;
        int part = tid & 7;
        const float4 v = ((const float4*)Xt)[row * 8 + part];
        float nrm = v.x * v.x + v.y * v.y + v.z * v.z + v.w * v.w;
        nrm += __shfl_xor(nrm, 1);
        nrm += __shfl_xor(nrm, 2);
        nrm += __shfl_xor(nrm, 4);
        half4v h = { (_Float16)(v.x * BSCALE), (_Float16)(v.y * BSCALE),
                     (_Float16)(v.z * BSCALE), (_Float16)(v.w * BSCALE) };
        *(half4v*)(Xth + row * DD + part * 4) = h;
        if (part == 0) {
            float cv = w[row] * __builtin_amdgcn_exp2f(-0.5f * LOG2E * nrm) * CENTER;
            ((floatx2*)c2)[row] = (floatx2){cv, cv};   // pre-duplicated splat
        }
    } else {                             // ---- sum(w) partials: 64 blocks
        int bid = b - 2176;
        float v = 0.f;
        for (int i = bid * 256 + threadIdx.x; i < NN; i += 64 * 256)
            v += w[i];
        #pragma unroll
        for (int o = 1; o < 64; o <<= 1) v += __shfl_xor(v, o);
        __shared__ float red[4];
        if ((threadIdx.x & 63) == 0) red[threadIdx.x >> 6] = v;
        __syncthreads();
        if (threadIdx.x == 0) swp[bid] = red[0] + red[1] + red[2] + red[3];
    }
}

// Main kernel: per wave, 64 queries x strip of 512 train points (16 B-pairs).
// R15 = R14 + packed-f32 epilogue: accumulators become float2 pairs
// (rows {0,1} and {2,3} of each MFMA tile) and the per-element fmac becomes
// half a v_pk_fma_f32. Epilogue VALU: 64 -> 48 ops/iteration. Everything
// else (single g buffer, distance-1 prefetch, XCD swizzle, 256-thread
// blocks, default launch bounds) unchanged from R14.
__global__ __launch_bounds__(256) void kde_main(
    const _Float16* __restrict__ Xh, const _Float16* __restrict__ Xth,
    const float* __restrict__ c2, float* __restrict__ S) {
    const int lane   = threadIdx.x & 63;
    const int wave   = threadIdx.x >> 6;
    const int quad   = lane >> 4;
    const int l16    = lane & 15;

    const int b      = blockIdx.x;            // 0..2047
    const int xcd    = b & 7;
    const int slot   = b >> 3;                // 0..255
    const int qx     = slot & 15;             // query tile 0..15
    const int strip  = xcd + 8 * (slot >> 4); // 0..127
    const int m_base = qx * 256 + wave * 64;
    const int n_beg  = strip * 512;

    // A fragments: 4 tiles of 16 queries, resident for the whole strip.
    half8 a[4];
    #pragma unroll
    for (int t = 0; t < 4; ++t)
        a[t] = *(const half8*)(Xh + (m_base + t * 16 + l16) * DD + quad * 8);

    floatx2 s2[4][2] = {};   // [tile][row-pair]; rows r = 2*p + component
    const floatx4 cbias = {BIAS_F, BIAS_F, BIAS_F, BIAS_F};

    const _Float16* bp = Xth + (size_t)(n_beg + l16) * DD + quad * 8;
    const floatx2*  cp = ((const floatx2*)c2) + n_beg + l16;

    // Prologue: load pair 0.
    half8 b0 = *(const half8*)bp;
    half8 b1 = *(const half8*)(bp + 16 * DD);
    floatx2 c0 = cp[0], c1 = cp[16];

    for (int it = 0; it < 16; ++it) {
        // 8 MFMAs on the current pair (single g buffer).
        floatx4 g[4][2];
        #pragma unroll
        for (int t = 0; t < 4; ++t) {
            g[t][0] = __builtin_amdgcn_mfma_f32_16x16x32_f16(a[t], b0, cbias, 0, 0, 0);
            g[t][1] = __builtin_amdgcn_mfma_f32_16x16x32_f16(a[t], b1, cbias, 0, 0, 0);
        }
        floatx2 ce0 = c0, ce1 = c1;

        // Distance-1 prefetch of the next pair (last iter over-reads one
        // pair into the adjacent ws regions -- dead values, in-bounds).
        bp += 32 * DD;
        cp += 32;
        b0 = *(const half8*)bp;
        b1 = *(const half8*)(bp + 16 * DD);
        c0 = cp[0];
        c1 = cp[16];

        // Epilogue: cvt(saturating) per element + packed FMA per row-pair.
        #pragma unroll
        for (int t = 0; t < 4; ++t) {
            #pragma unroll
            for (int p = 0; p < 2; ++p) {
                floatx2 e0 = { fexp_term(g[t][0][2 * p]),
                               fexp_term(g[t][0][2 * p + 1]) };
                pk_fma(s2[t][p], ce0, e0);
                floatx2 e1 = { fexp_term(g[t][1][2 * p]),
                               fexp_term(g[t][1][2 * p + 1]) };
                pk_fma(s2[t][p], ce1, e1);
            }
        }
    }

    // Reduce over the 16 columns (lanes sharing the same quad), then atomic.
    #pragma unroll
    for (int t = 0; t < 4; ++t) {
        #pragma unroll
        for (int p = 0; p < 2; ++p) {
            #pragma unroll
            for (int j = 0; j < 2; ++j) {
                float v = s2[t][p][j];
                v += __shfl_xor(v, 1);
                v += __shfl_xor(v, 2);
                v += __shfl_xor(v, 4);
                v += __shfl_xor(v, 8);
                if (l16 == 0)
                    atomicAdd(&S[m_base + t * 16 + quad * 4 + 2 * p + j], v);
            }
        }
    }
}

// Finalize: 16 blocks x 256 threads; sums the 64 w-partials via shuffle.
__global__ void finalize(const float* __restrict__ S, const float* __restrict__ qn,
                         const float* __restrict__ swp, float* __restrict__ out) {
    float pv = swp[threadIdx.x & 63];
    pv += __shfl_xor(pv, 1);
    pv += __shfl_xor(pv, 2);
    pv += __shfl_xor(pv, 4);
    pv += __shfl_xor(pv, 8);
    pv += __shfl_xor(pv, 16);
    pv += __shfl_xor(pv, 32);
    float lsw = logf(pv);
    int i = blockIdx.x * blockDim.x + threadIdx.x;
    out[i] = logf(S[i]) - qn[i] - HALF_D_LOG_2PI - lsw;
}

extern "C" void kernel_launch(void* const* d_in, const int* in_sizes, int n_in,
                              void* d_out, int out_size, void* d_ws, size_t ws_size,
                              hipStream_t stream) {
    const float* X  = (const float*)d_in[0];
    const float* Xt = (const float*)d_in[1];
    const float* w  = (const float*)d_in[2];
    float* out = (float*)d_out;

    char* ws = (char*)d_ws;
    _Float16* Xh   = (_Float16*)(ws);
    _Float16* Xth  = (_Float16*)(ws + 262144);
    float*    c2   = (float*)(ws + 4456448);
    float*    qn   = (float*)(ws + 4980736);
    float*    S    = (float*)(ws + 4997120);
    float*    swp  = (float*)(ws + 5013504);

    prep_all<<<2240, 256, 0, stream>>>(X, Xt, w, Xh, qn, Xth, c2, S, swp);
    kde_main<<<2048, 256, 0, stream>>>(Xh, Xth, c2, S);
    finalize<<<QN / 256, 256, 0, stream>>>(S, qn, swp, out);
}

// Round 11
// 106.269 us; speedup vs baseline: 1.0131x; 1.0131x over previous
//
#include <hip/hip_runtime.h>
#include <math.h>

// Problem constants (fixed by the reference): Q=4096 queries, N=65536 train, D=32.
#define QN 4096
#define NN 65536
#define DD 32

typedef __attribute__((ext_vector_type(8))) _Float16 half8;
typedef __attribute__((ext_vector_type(4))) _Float16 half4v;
typedef __attribute__((ext_vector_type(4))) float floatx4;
typedef __attribute__((ext_vector_type(2))) float floatx2;

#define LOG2E 1.4426950408889634f
#define HALF_D_LOG_2PI 29.40603306254953f   // 16 * ln(2*pi)

// exp2-in-MFMA scaling: A = x*log2(e)*2^11, B = y*2^12, C = 127*2^23.
// MFMA emits v = (127 + x.y*log2e)*2^23 == the float bit pattern of
// 2^(x.y*log2e) under the linear-mantissa approximation.
// Epilogue per element: one v_cvt_u32_f32 (saturating: neg -> 0, the
// load-bearing lower clamp) + HALF a v_pk_fma_f32 (packed pairs of rows).
#define ASCALE 2954.6394357789634f   // log2(e) * 2048
#define BSCALE 4096.0f               // 2^12
#define BIAS_F 1065353216.0f         // 127 * 2^23
#define CENTER 0.970656f             // centers the one-sided approx error

__device__ __forceinline__ float fexp_term(float v) {
    unsigned u;
    asm("v_cvt_u32_f32 %0, %1" : "=v"(u) : "v"(v));  // saturating: neg -> 0
    return __uint_as_float(u);
}

// s += c * e, two f32 lanes per instruction (VOP3P packed FP32).
__device__ __forceinline__ void pk_fma(floatx2& s, floatx2 c, floatx2 e) {
    asm("v_pk_fma_f32 %0, %1, %2, %0" : "+v"(s) : "v"(c), "v"(e));
}

// ---------------------------------------------------------------------------
// Workspace layout (bytes):
//   Xh    @ 0        : QN*DD*2 = 262144   (_Float16, X * ASCALE)
//   Xth   @ 262144   : NN*DD*2 = 4194304  (_Float16, X_train * BSCALE)
//   c2    @ 4456448  : NN*8    = 524288   (float2 {c_j, c_j},
//                                          c_j = CENTER*w_j*exp(-||y_j||^2/2))
//   qn    @ 4980736  : QN*4    = 16384    (||x_i||^2 / 2, nat units)
//   S     @ 4997120  : QN*4    = 16384    (zeroed by prep_all)
//   swp   @ 5013504  : 64*4    = 256      (per-block partial sums of w)
// kde_main's distance-2 prefetch over-reads <= 2 pairs past the strip end;
// for the last strip the b-over-read lands in c2 (4 KB deep, 512 KB region)
// and the c-over-read lands <= 512 B into qn -- both in-bounds, discarded.
// ---------------------------------------------------------------------------

__global__ __launch_bounds__(256) void prep_all(
    const float* __restrict__ X, const float* __restrict__ Xt,
    const float* __restrict__ w, _Float16* __restrict__ Xh,
    float* __restrict__ qn, _Float16* __restrict__ Xth,
    float* __restrict__ c2, float* __restrict__ S,
    float* __restrict__ swp) {
    const int b = blockIdx.x;
    if (b < 128) {                       // ---- prep X: QN rows, 8 lanes/row
        int tid  = b * 256 + threadIdx.x;
        int row  = tid >> 3;
        int part = tid & 7;
        const float4 v = ((const float4*)X)[row * 8 + part];
        float nrm = v.x * v.x + v.y * v.y + v.z * v.z + v.w * v.w;
        nrm += __shfl_xor(nrm, 1);
        nrm += __shfl_xor(nrm, 2);
        nrm += __shfl_xor(nrm, 4);
        half4v h = { (_Float16)(v.x * ASCALE), (_Float16)(v.y * ASCALE),
                     (_Float16)(v.z * ASCALE), (_Float16)(v.w * ASCALE) };
        *(half4v*)(Xh + row * DD + part * 4) = h;
        if (part == 0) qn[row] = 0.5f * nrm;
        if (tid < QN) S[tid] = 0.f;      // fused zeroing of S
    } else if (b < 2176) {               // ---- prep X_train: NN rows
        int tid  = (b - 128) * 256 + threadIdx.x;
        int row  = tid >> 3;
        int part = tid & 7;
        const float4 v = ((const float4*)Xt)[row * 8 + part];
        float nrm = v.x * v.x + v.y * v.y + v.z * v.z + v.w * v.w;
        nrm += __shfl_xor(nrm, 1);
        nrm += __shfl_xor(nrm, 2);
        nrm += __shfl_xor(nrm, 4);
        half4v h = { (_Float16)(v.x * BSCALE), (_Float16)(v.y * BSCALE),
                     (_Float16)(v.z * BSCALE), (_Float16)(v.w * BSCALE) };
        *(half4v*)(Xth + row * DD + part * 4) = h;
        if (part == 0) {
            float cv = w[row] * __builtin_amdgcn_exp2f(-0.5f * LOG2E * nrm) * CENTER;
            ((floatx2*)c2)[row] = (floatx2){cv, cv};   // pre-duplicated splat
        }
    } else {                             // ---- sum(w) partials: 64 blocks
        int bid = b - 2176;
        float v = 0.f;
        for (int i = bid * 256 + threadIdx.x; i < NN; i += 64 * 256)
            v += w[i];
        #pragma unroll
        for (int o = 1; o < 64; o <<= 1) v += __shfl_xor(v, o);
        __shared__ float red[4];
        if ((threadIdx.x & 63) == 0) red[threadIdx.x >> 6] = v;
        __syncthreads();
        if (threadIdx.x == 0) swp[bid] = red[0] + red[1] + red[2] + red[3];
    }
}

// Main kernel: per wave, 64 queries x strip of 512 train points (16 B-pairs).
// R16 = R15 + distance-2 prefetch. R15 counters: dur 44.5us, VALUBusy 43%,
// MfmaUtil 14%, HBM 3% -- no pipe saturated, 57% idle => load-latency
// stalls (4 co-resident blocks/CU stream 4 different 32KB strips through a
// 32KB L1, so b/c loads are ~200-400cy L2 accesses; distance-1 prefetch
// gives only ~1 epilogue of cover). Double-buffering the incoming pair
// (named A/B buffers, 2-phase unrolled loop -- no runtime-indexed vector
// arrays) stretches load->use to ~2 epilogues + 1 MFMA block. +12 VGPR
// (56 -> ~68), combined with ~52 AGPR stays <= 128/wave: occupancy cap
// unchanged. Single g buffer, XCD swizzle, 256-thread blocks, default
// launch bounds all unchanged (R11/R13 lessons).
__global__ __launch_bounds__(256) void kde_main(
    const _Float16* __restrict__ Xh, const _Float16* __restrict__ Xth,
    const float* __restrict__ c2, float* __restrict__ S) {
    const int lane   = threadIdx.x & 63;
    const int wave   = threadIdx.x >> 6;
    const int quad   = lane >> 4;
    const int l16    = lane & 15;

    const int b      = blockIdx.x;            // 0..2047
    const int xcd    = b & 7;
    const int slot   = b >> 3;                // 0..255
    const int qx     = slot & 15;             // query tile 0..15
    const int strip  = xcd + 8 * (slot >> 4); // 0..127
    const int m_base = qx * 256 + wave * 64;
    const int n_beg  = strip * 512;

    // A fragments: 4 tiles of 16 queries, resident for the whole strip.
    half8 a[4];
    #pragma unroll
    for (int t = 0; t < 4; ++t)
        a[t] = *(const half8*)(Xh + (m_base + t * 16 + l16) * DD + quad * 8);

    floatx2 s2[4][2] = {};   // [tile][row-pair]; rows r = 2*p + component
    const floatx4 cbias = {BIAS_F, BIAS_F, BIAS_F, BIAS_F};

    const _Float16* bp = Xth + (size_t)(n_beg + l16) * DD + quad * 8;
    const floatx2*  cp = ((const floatx2*)c2) + n_beg + l16;

    // Prologue: load pairs 0 (buffer A) and 1 (buffer B).
    half8 b0a = *(const half8*)bp;
    half8 b1a = *(const half8*)(bp + 16 * DD);
    floatx2 c0a = cp[0], c1a = cp[16];
    bp += 32 * DD; cp += 32;
    half8 b0b = *(const half8*)bp;
    half8 b1b = *(const half8*)(bp + 16 * DD);
    floatx2 c0b = cp[0], c1b = cp[16];

    // One phase: 8 MFMAs on the buffered pair, refill that buffer with the
    // pair two steps ahead (distance-2), then the cvt+pk_fma epilogue.
#define KDE_PHASE(B0, B1, C0, C1)                                          \
    {                                                                      \
        floatx4 g[4][2];                                                   \
        _Pragma("unroll")                                                  \
        for (int t = 0; t < 4; ++t) {                                      \
            g[t][0] = __builtin_amdgcn_mfma_f32_16x16x32_f16(a[t], B0, cbias, 0, 0, 0); \
            g[t][1] = __builtin_amdgcn_mfma_f32_16x16x32_f16(a[t], B1, cbias, 0, 0, 0); \
        }                                                                  \
        floatx2 ce0 = C0, ce1 = C1;                                        \
        bp += 32 * DD;                                                     \
        cp += 32;                                                          \
        B0 = *(const half8*)bp;                                            \
        B1 = *(const half8*)(bp + 16 * DD);                                \
        C0 = cp[0];                                                        \
        C1 = cp[16];                                                       \
        _Pragma("unroll")                                                  \
        for (int t = 0; t < 4; ++t) {                                      \
            _Pragma("unroll")                                              \
            for (int p = 0; p < 2; ++p) {                                  \
                floatx2 e0 = { fexp_term(g[t][0][2 * p]),                  \
                               fexp_term(g[t][0][2 * p + 1]) };            \
                pk_fma(s2[t][p], ce0, e0);                                 \
                floatx2 e1 = { fexp_term(g[t][1][2 * p]),                  \
                               fexp_term(g[t][1][2 * p + 1]) };            \
                pk_fma(s2[t][p], ce1, e1);                                 \
            }                                                              \
        }                                                                  \
    }

    for (int it = 0; it < 16; it += 2) {
        KDE_PHASE(b0a, b1a, c0a, c1a)   // consumes pair it,   prefetches it+2
        KDE_PHASE(b0b, b1b, c0b, c1b)   // consumes pair it+1, prefetches it+3
    }
#undef KDE_PHASE

    // Reduce over the 16 columns (lanes sharing the same quad), then atomic.
    #pragma unroll
    for (int t = 0; t < 4; ++t) {
        #pragma unroll
        for (int p = 0; p < 2; ++p) {
            #pragma unroll
            for (int j = 0; j < 2; ++j) {
                float v = s2[t][p][j];
                v += __shfl_xor(v, 1);
                v += __shfl_xor(v, 2);
                v += __shfl_xor(v, 4);
                v += __shfl_xor(v, 8);
                if (l16 == 0)
                    atomicAdd(&S[m_base + t * 16 + quad * 4 + 2 * p + j], v);
            }
        }
    }
}

// Finalize: 16 blocks x 256 threads; sums the 64 w-partials via shuffle.
__global__ void finalize(const float* __restrict__ S, const float* __restrict__ qn,
                         const float* __restrict__ swp, float* __restrict__ out) {
    float pv = swp[threadIdx.x & 63];
    pv += __shfl_xor(pv, 1);
    pv += __shfl_xor(pv, 2);
    pv += __shfl_xor(pv, 4);
    pv += __shfl_xor(pv, 8);
    pv += __shfl_xor(pv, 16);
    pv += __shfl_xor(pv, 32);
    float lsw = logf(pv);
    int i = blockIdx.x * blockDim.x + threadIdx.x;
    out[i] = logf(S[i]) - qn[i] - HALF_D_LOG_2PI - lsw;
}

extern "C" void kernel_launch(void* const* d_in, const int* in_sizes, int n_in,
                              void* d_out, int out_size, void* d_ws, size_t ws_size,
                              hipStream_t stream) {
    const float* X  = (const float*)d_in[0];
    const float* Xt = (const float*)d_in[1];
    const float* w  = (const float*)d_in[2];
    float* out = (float*)d_out;

    char* ws = (char*)d_ws;
    _Float16* Xh   = (_Float16*)(ws);
    _Float16* Xth  = (_Float16*)(ws + 262144);
    float*    c2   = (float*)(ws + 4456448);
    float*    qn   = (float*)(ws + 4980736);
    float*    S    = (float*)(ws + 4997120);
    float*    swp  = (float*)(ws + 5013504);

    prep_all<<<2240, 256, 0, stream>>>(X, Xt, w, Xh, qn, Xth, c2, S, swp);
    kde_main<<<2048, 256, 0, stream>>>(Xh, Xth, c2, S);
    finalize<<<QN / 256, 256, 0, stream>>>(S, qn, swp, out);
}

// Round 15
// 100.846 us; speedup vs baseline: 1.0676x; 1.0538x over previous
//
#include <hip/hip_runtime.h>
#include <math.h>

// Problem constants (fixed by the reference): Q=4096 queries, N=65536 train, D=32.
#define QN 4096
#define NN 65536
#define DD 32

typedef __attribute__((ext_vector_type(8))) _Float16 half8;
typedef __attribute__((ext_vector_type(4))) _Float16 half4v;
typedef __attribute__((ext_vector_type(4))) float floatx4;

#define LOG2E 1.4426950408889634f
#define HALF_D_LOG_2PI 29.40603306254953f   // 16 * ln(2*pi)

// exp2-in-MFMA scaling: A = x*log2(e)*2^11, B = y*2^12, C = 127*2^23.
// MFMA emits v = (127 + x.y*log2e)*2^23 == the float bit pattern of
// 2^(x.y*log2e) under the linear-mantissa approximation.
// Epilogue per element: one v_cvt_u32_f32 (saturating: neg -> 0, the
// load-bearing lower clamp) + one v_fmac_f32. R17 lesson: the R15 packed
// epilogue (floatx2{cvt,cvt} + tied-operand v_pk_fma_f32) made the compiler
// emit pair-alignment movs -- measured ~180 VALU ops/iter (VALUBusy 44% at
// 3 waves/SIMD) vs ~64 source-visible, and R15/R16 totals (107.7/106.3us)
// regressed vs R14's scalar epilogue (101.1us). Scalar cvt+fmac gives the
// compiler nothing to pad.
#define ASCALE 2954.6394357789634f   // log2(e) * 2048
#define BSCALE 4096.0f               // 2^12
#define BIAS_F 1065353216.0f         // 127 * 2^23
#define CENTER 0.970656f             // centers the one-sided approx error

__device__ __forceinline__ float fexp_term(float v) {
    unsigned u;
    asm("v_cvt_u32_f32 %0, %1" : "=v"(u) : "v"(v));  // saturating: neg -> 0
    return __uint_as_float(u);
}

// ---------------------------------------------------------------------------
// Workspace layout (bytes):
//   Xh    @ 0        : QN*DD*2 = 262144   (_Float16, X * ASCALE)
//   Xth   @ 262144   : NN*DD*2 = 4194304  (_Float16, X_train * BSCALE)
//   c     @ 4456448  : NN*4    = 262144   (CENTER * w_j * exp(-||y_j||^2/2))
//   qn    @ 4980736  : QN*4    = 16384    (||x_i||^2 / 2, nat units)
//   S     @ 4997120  : QN*4    = 16384    (zeroed by prep_all)
//   swp   @ 5013504  : 64*4    = 256      (per-block partial sums of w)
// kde_main's distance-2 prefetch over-reads <= 2 pairs past the strip end;
// for the last strip the b-over-read lands in the c region (4 KB deep) and
// the c-over-read lands in the slack before qn -- in-bounds, discarded.
// ---------------------------------------------------------------------------

__global__ __launch_bounds__(256) void prep_all(
    const float* __restrict__ X, const float* __restrict__ Xt,
    const float* __restrict__ w, _Float16* __restrict__ Xh,
    float* __restrict__ qn, _Float16* __restrict__ Xth,
    float* __restrict__ c, float* __restrict__ S,
    float* __restrict__ swp) {
    const int b = blockIdx.x;
    if (b < 128) {                       // ---- prep X: QN rows, 8 lanes/row
        int tid  = b * 256 + threadIdx.x;
        int row  = tid >> 3;
        int part = tid & 7;
        const float4 v = ((const float4*)X)[row * 8 + part];
        float nrm = v.x * v.x + v.y * v.y + v.z * v.z + v.w * v.w;
        nrm += __shfl_xor(nrm, 1);
        nrm += __shfl_xor(nrm, 2);
        nrm += __shfl_xor(nrm, 4);
        half4v h = { (_Float16)(v.x * ASCALE), (_Float16)(v.y * ASCALE),
                     (_Float16)(v.z * ASCALE), (_Float16)(v.w * ASCALE) };
        *(half4v*)(Xh + row * DD + part * 4) = h;
        if (part == 0) qn[row] = 0.5f * nrm;
        if (tid < QN) S[tid] = 0.f;      // fused zeroing of S
    } else if (b < 2176) {               // ---- prep X_train: NN rows
        int tid  = (b - 128) * 256 + threadIdx.x;
        int row  = tid >> 3;
        int part = tid & 7;
        const float4 v = ((const float4*)Xt)[row * 8 + part];
        float nrm = v.x * v.x + v.y * v.y + v.z * v.z + v.w * v.w;
        nrm += __shfl_xor(nrm, 1);
        nrm += __shfl_xor(nrm, 2);
        nrm += __shfl_xor(nrm, 4);
        half4v h = { (_Float16)(v.x * BSCALE), (_Float16)(v.y * BSCALE),
                     (_Float16)(v.z * BSCALE), (_Float16)(v.w * BSCALE) };
        *(half4v*)(Xth + row * DD + part * 4) = h;
        if (part == 0)
            c[row] = w[row] * __builtin_amdgcn_exp2f(-0.5f * LOG2E * nrm) * CENTER;
    } else {                             // ---- sum(w) partials: 64 blocks
        int bid = b - 2176;
        float v = 0.f;
        for (int i = bid * 256 + threadIdx.x; i < NN; i += 64 * 256)
            v += w[i];
        #pragma unroll
        for (int o = 1; o < 64; o <<= 1) v += __shfl_xor(v, o);
        __shared__ float red[4];
        if ((threadIdx.x & 63) == 0) red[threadIdx.x >> 6] = v;
        __syncthreads();
        if (threadIdx.x == 0) swp[bid] = red[0] + red[1] + red[2] + red[3];
    }
}

// Main kernel: per wave, 64 queries x strip of 512 train points (16 B-pairs).
// R17 = R16 structure (distance-2 A/B buffers -- kept: null on dur but
// VGPR 56->48 and occupancy 31->38%, i.e. free) with the R14 scalar
// epilogue restored (see header comment: pk_fma experiment measured as a
// regression; VALU is the dominant pipe at 44% busy and the packed path's
// hidden movs are the fat). Single g buffer, XCD swizzle, 256-thread
// blocks, default launch bounds unchanged.
__global__ __launch_bounds__(256) void kde_main(
    const _Float16* __restrict__ Xh, const _Float16* __restrict__ Xth,
    const float* __restrict__ c, float* __restrict__ S) {
    const int lane   = threadIdx.x & 63;
    const int wave   = threadIdx.x >> 6;
    const int quad   = lane >> 4;
    const int l16    = lane & 15;

    const int b      = blockIdx.x;            // 0..2047
    const int xcd    = b & 7;
    const int slot   = b >> 3;                // 0..255
    const int qx     = slot & 15;             // query tile 0..15
    const int strip  = xcd + 8 * (slot >> 4); // 0..127
    const int m_base = qx * 256 + wave * 64;
    const int n_beg  = strip * 512;

    // A fragments: 4 tiles of 16 queries, resident for the whole strip.
    half8 a[4];
    #pragma unroll
    for (int t = 0; t < 4; ++t)
        a[t] = *(const half8*)(Xh + (m_base + t * 16 + l16) * DD + quad * 8);

    float s[4][4] = {};
    const floatx4 cbias = {BIAS_F, BIAS_F, BIAS_F, BIAS_F};

    const _Float16* bp = Xth + (size_t)(n_beg + l16) * DD + quad * 8;
    const float*    cp = c + n_beg + l16;

    // Prologue: load pairs 0 (buffer A) and 1 (buffer B).
    half8 b0a = *(const half8*)bp;
    half8 b1a = *(const half8*)(bp + 16 * DD);
    float c0a = cp[0], c1a = cp[16];
    bp += 32 * DD; cp += 32;
    half8 b0b = *(const half8*)bp;
    half8 b1b = *(const half8*)(bp + 16 * DD);
    float c0b = cp[0], c1b = cp[16];

    // One phase: 8 MFMAs on the buffered pair, refill that buffer with the
    // pair two steps ahead (distance-2), then the scalar cvt+fmac epilogue.
#define KDE_PHASE(B0, B1, C0, C1)                                          \
    {                                                                      \
        floatx4 g[4][2];                                                   \
        _Pragma("unroll")                                                  \
        for (int t = 0; t < 4; ++t) {                                      \
            g[t][0] = __builtin_amdgcn_mfma_f32_16x16x32_f16(a[t], B0, cbias, 0, 0, 0); \
            g[t][1] = __builtin_amdgcn_mfma_f32_16x16x32_f16(a[t], B1, cbias, 0, 0, 0); \
        }                                                                  \
        float ce0 = C0, ce1 = C1;                                          \
        bp += 32 * DD;                                                     \
        cp += 32;                                                          \
        B0 = *(const half8*)bp;                                            \
        B1 = *(const half8*)(bp + 16 * DD);                                \
        C0 = cp[0];                                                        \
        C1 = cp[16];                                                       \
        _Pragma("unroll")                                                  \
        for (int t = 0; t < 4; ++t) {                                      \
            _Pragma("unroll")                                              \
            for (int r = 0; r < 4; ++r) {                                  \
                s[t][r] += ce0 * fexp_term(g[t][0][r]);                    \
                s[t][r] += ce1 * fexp_term(g[t][1][r]);                    \
            }                                                              \
        }                                                                  \
    }

    for (int it = 0; it < 16; it += 2) {
        KDE_PHASE(b0a, b1a, c0a, c1a)   // consumes pair it,   prefetches it+2
        KDE_PHASE(b0b, b1b, c0b, c1b)   // consumes pair it+1, prefetches it+3
    }
#undef KDE_PHASE

    // Reduce over the 16 columns (lanes sharing the same quad), then atomic.
    #pragma unroll
    for (int t = 0; t < 4; ++t) {
        #pragma unroll
        for (int r = 0; r < 4; ++r) {
            float v = s[t][r];
            v += __shfl_xor(v, 1);
            v += __shfl_xor(v, 2);
            v += __shfl_xor(v, 4);
            v += __shfl_xor(v, 8);
            if (l16 == 0)
                atomicAdd(&S[m_base + t * 16 + quad * 4 + r], v);
        }
    }
}

// Finalize: 16 blocks x 256 threads; sums the 64 w-partials via shuffle.
__global__ void finalize(const float* __restrict__ S, const float* __restrict__ qn,
                         const float* __restrict__ swp, float* __restrict__ out) {
    float pv = swp[threadIdx.x & 63];
    pv += __shfl_xor(pv, 1);
    pv += __shfl_xor(pv, 2);
    pv += __shfl_xor(pv, 4);
    pv += __shfl_xor(pv, 8);
    pv += __shfl_xor(pv, 16);
    pv += __shfl_xor(pv, 32);
    float lsw = logf(pv);
    int i = blockIdx.x * blockDim.x + threadIdx.x;
    out[i] = logf(S[i]) - qn[i] - HALF_D_LOG_2PI - lsw;
}

extern "C" void kernel_launch(void* const* d_in, const int* in_sizes, int n_in,
                              void* d_out, int out_size, void* d_ws, size_t ws_size,
                              hipStream_t stream) {
    const float* X  = (const float*)d_in[0];
    const float* Xt = (const float*)d_in[1];
    const float* w  = (const float*)d_in[2];
    float* out = (float*)d_out;

    char* ws = (char*)d_ws;
    _Float16* Xh   = (_Float16*)(ws);
    _Float16* Xth  = (_Float16*)(ws + 262144);
    float*    c    = (float*)(ws + 4456448);
    float*    qn   = (float*)(ws + 4980736);
    float*    S    = (float*)(ws + 4997120);
    float*    swp  = (float*)(ws + 5013504);

    prep_all<<<2240, 256, 0, stream>>>(X, Xt, w, Xh, qn, Xth, c, S, swp);
    kde_main<<<2048, 256, 0, stream>>>(Xh, Xth, c, S);
    finalize<<<QN / 256, 256, 0, stream>>>(S, qn, swp, out);
}